// Round 4
// baseline (606.006 us; speedup 1.0000x reference)
//
#include <hip/hip_runtime.h>
#include <stdint.h>

// DynamicQuantizedLinear on MI355X.
// Harness-normalized dtypes assumed: d_in = {x: f32 [2048,4096], weight_q: int32
// [11008,4096], scale: f32 [11008], bias: f32 [11008]}, d_out = f32 [2048,11008].
//
// Pass 1 (prepass): d_ws <- X16 = fp16(x); W16[n,k] = fp16(wq[n,k] * scale[n]).
//   W16 is bit-identical to the reference's materialized weight_deq (fp16*fp16
//   correctly rounded via f32 mul + RN-to-fp16). ~320 MB HBM traffic, ~55 us.
// Pass 2: f16 GEMM, m97 structure (128x128 tile, BK=32, 4 waves 2x2,
//   mfma_f32_16x16x32_f16, global_load_lds width 16, double-buffered LDS,
//   one barrier per K-step). Epilogue matches the reference's rounding order:
//   fp16(dot) first, then +bias in fp16, store f32.

#define M_DIM 2048
#define N_DIM 11008
#define K_DIM 4096
#define BM 128
#define BN 128
#define BK 32
#define NKT (K_DIM / BK)

#define NWQ (N_DIM * K_DIM / 4)   // W quads (int32x4 -> f16x4): 11,272,192
#define NXQ (M_DIM * K_DIM / 4)   // x quads (f32x4  -> f16x4):  2,097,152

typedef _Float16 f16x4 __attribute__((ext_vector_type(4)));
typedef _Float16 f16x8 __attribute__((ext_vector_type(8)));
typedef float    f32x4 __attribute__((ext_vector_type(4)));

// ---------------- pass 1: dequantize W to fp16, downcast x ----------------
__global__ __launch_bounds__(256)
void prepass(const float* __restrict__ X, const int* __restrict__ WQ,
             const float* __restrict__ SC,
             _Float16* __restrict__ X16, _Float16* __restrict__ W16)
{
  const int stride = gridDim.x * blockDim.x;
  for (int i = blockIdx.x * blockDim.x + threadIdx.x; i < NWQ + NXQ; i += stride) {
    if (i < NWQ) {
      const int4 w = ((const int4*)WQ)[i];
      const float s = SC[i >> 10];               // 1024 quads per K-row
      f16x4 o = { (_Float16)(w.x * s), (_Float16)(w.y * s),
                  (_Float16)(w.z * s), (_Float16)(w.w * s) };
      ((f16x4*)W16)[i] = o;
    } else {
      const int j = i - NWQ;
      const float4 v = ((const float4*)X)[j];
      f16x4 o = { (_Float16)v.x, (_Float16)v.y, (_Float16)v.z, (_Float16)v.w };
      ((f16x4*)X16)[j] = o;
    }
  }
}

// ---------------- pass 2: f16 GEMM (m97 structure) ----------------
// async global->LDS, 16B per lane. LDS dest = wave-uniform base + lane*16.
__device__ __forceinline__ void async_cp16(void* lds, const void* g) {
  auto l = (__attribute__((address_space(3))) uint32_t*)(uintptr_t)lds; // low 32b = LDS offset
  auto p = (const __attribute__((address_space(1))) uint32_t*)(uintptr_t)g;
  __builtin_amdgcn_global_load_lds(p, l, 16, 0, 0);
}

__global__ __launch_bounds__(256, 3)
void qlinear_gemm(const _Float16* __restrict__ A, const _Float16* __restrict__ B,
                  const float* __restrict__ BI, float* __restrict__ O)
{
  __shared__ __align__(16) _Float16 sA[2][BM * BK];   // 16 KB
  __shared__ __align__(16) _Float16 sB[2][BN * BK];   // 16 KB

  const int t    = threadIdx.x;
  const int lane = t & 63;
  const int wv   = t >> 6;
  const int wr   = wv >> 1;      // wave row (0..1): 64 M-rows each
  const int wc   = wv & 1;       // wave col (0..1): 64 N-cols each
  const int fr   = lane & 15;    // A/B fragment row; C col
  const int fq   = lane >> 4;    // k-group (0..3)

  const int nbn = N_DIM / BN;    // 86
  const int m0  = (blockIdx.x / nbn) * BM;
  const int n0  = (blockIdx.x % nbn) * BN;

  // staging: 16B chunks, chunk c = t: row (c>>2), quarter (c&3). LDS is linear
  // in chunk order (global_load_lds writes base + lane*16) == row-major [row][BK].
  const _Float16* gA0 = A + (size_t)(m0 + (t >> 2)) * K_DIM + (t & 3) * 8;
  const _Float16* gB0 = B + (size_t)(n0 + (t >> 2)) * K_DIM + (t & 3) * 8;
  const int wbase = t & 0xC0;                // wave-uniform chunk base
  _Float16* lA = &sA[0][0] + wbase * 8;      // chunk*16B = chunk*8 f16
  _Float16* lB = &sB[0][0] + wbase * 8;

  f32x4 acc[4][4] = {};

#define STAGE(buf, kt) do {                                                    \
    const int ko_ = (kt) * BK;                                                 \
    async_cp16((void*)(lA + (buf) * (BM * BK)),        gA0 + ko_);             \
    async_cp16((void*)(lA + (buf) * (BM * BK) + 2048), gA0 + (size_t)64 * K_DIM + ko_); \
    async_cp16((void*)(lB + (buf) * (BN * BK)),        gB0 + ko_);             \
    async_cp16((void*)(lB + (buf) * (BN * BK) + 2048), gB0 + (size_t)64 * K_DIM + ko_); \
  } while (0)

  STAGE(0, 0);
  __syncthreads();   // implicit vmcnt(0) drain: tile 0 ready

  for (int kt = 0; kt < NKT; ++kt) {
    const int cur = kt & 1;
    if (kt + 1 < NKT) STAGE(cur ^ 1, kt + 1);   // async prefetch overlaps compute

    const _Float16* aB = &sA[cur][0] + (wr * 64 + fr) * BK + fq * 8;
    const _Float16* bB = &sB[cur][0] + (wc * 64 + fr) * BK + fq * 8;

    f16x8 af[4], bf[4];
#pragma unroll
    for (int i = 0; i < 4; ++i) af[i] = *(const f16x8*)(aB + i * 16 * BK); // ds_read_b128
#pragma unroll
    for (int i = 0; i < 4; ++i) bf[i] = *(const f16x8*)(bB + i * 16 * BK);

#pragma unroll
    for (int mi = 0; mi < 4; ++mi)
#pragma unroll
      for (int ni = 0; ni < 4; ++ni)
        acc[mi][ni] = __builtin_amdgcn_mfma_f32_16x16x32_f16(af[mi], bf[ni], acc[mi][ni], 0, 0, 0);

    __syncthreads();  // drains prefetch vmcnt + lgkm; one barrier per K-step
  }

  // epilogue: C/D layout col=lane&15, row=(lane>>4)*4+j. Scale folded into W16.
  // Match reference rounding order: fp16(dot), then + bias in fp16, store f32.
  const int om = m0 + wr * 64;
  const int on = n0 + wc * 64;
#pragma unroll
  for (int ni = 0; ni < 4; ++ni) {
    const int n = on + ni * 16 + fr;
    const float b = BI[n];
#pragma unroll
    for (int mi = 0; mi < 4; ++mi) {
      const int m = om + mi * 16 + fq * 4;
#pragma unroll
      for (int j = 0; j < 4; ++j) {
        const _Float16 h = (_Float16)acc[mi][ni][j];        // fp16(dot)
        const _Float16 r = (_Float16)((float)h + b);        // fp16(h + bias)
        O[(size_t)(m + j) * N_DIM + n] = (float)r;
      }
    }
  }
#undef STAGE
}

extern "C" void kernel_launch(void* const* d_in, const int* in_sizes, int n_in,
                              void* d_out, int out_size, void* d_ws, size_t ws_size,
                              hipStream_t stream) {
  const float* x  = (const float*)d_in[0];
  const int*   wq = (const int*)d_in[1];
  const float* sc = (const float*)d_in[2];
  const float* bi = (const float*)d_in[3];
  float* out = (float*)d_out;

  _Float16* x16 = (_Float16*)d_ws;                                      // 16,777,216 B
  _Float16* w16 = (_Float16*)((char*)d_ws + (size_t)M_DIM * K_DIM * 2); // 90,177,536 B
  const size_t need = (size_t)M_DIM * K_DIM * 2 + (size_t)N_DIM * K_DIM * 2;
  if (ws_size < need) return;  // ws too small: leave output poisoned (clear signal)

  prepass<<<dim3(2048), dim3(256), 0, stream>>>(x, wq, sc, x16, w16);

  dim3 grid((M_DIM / BM) * (N_DIM / BN));   // 16 * 86 = 1376 blocks
  qlinear_gemm<<<grid, dim3(256), 0, stream>>>(x16, w16, bi, out);
}

// Round 9
// 525.078 us; speedup vs baseline: 1.1541x; 1.1541x over previous
//
#include <hip/hip_runtime.h>
#include <stdint.h>

// DynamicQuantizedLinear on MI355X.
// d_in = {x: f32 [2048,4096], weight_q: int32 [11008,4096], scale: f32 [11008],
//         bias: f32 [11008]}, d_out = f32 [2048,11008].
//
// Pass 1a/1b (streaming prepass, exact grids, 1 load + 1 store per thread):
//   W16[n,k] = fp16(wq[n,k] * scale[n])  (bit-identical to reference's weight_deq)
//   X16      = fp16(x)                   (exact; values born fp16)
// Pass 2: f16 GEMM, m97 structure (128x128 tile, BK=32, 4 waves 2x2,
//   mfma_f32_16x16x32_f16, global_load_lds width 16, double-buffered LDS, one
//   barrier per K-step). Grid: bm-fastest (W-panel reuse) + XCD-chunked swizzle.
//   __launch_bounds__(256,5): LDS (32KB/block) allows 5 blocks/CU; VGPR=52 is
//   nowhere near limiting. R4 ran at 34.6% occupancy only because the old
//   bound requested 3 waves/EU. More resident blocks -> barrier-drain overlap.
//   Epilogue matches reference rounding: fp16(dot), then +bias in fp16, f32 store.

#define M_DIM 2048
#define N_DIM 11008
#define K_DIM 4096
#define BM 128
#define BN 128
#define BK 32
#define NKT (K_DIM / BK)

#define NWQ (N_DIM * K_DIM / 4)   // W quads: 11,272,192 = 44032 * 256
#define NXQ (M_DIM * K_DIM / 4)   // x quads:  2,097,152 =  8192 * 256

typedef _Float16 f16x4 __attribute__((ext_vector_type(4)));
typedef _Float16 f16x8 __attribute__((ext_vector_type(8)));
typedef float    f32x4 __attribute__((ext_vector_type(4)));

// ---------------- pass 1a: dequantize W to fp16 (pure streaming) ----------------
__global__ __launch_bounds__(256)
void prep_w(const int* __restrict__ WQ, const float* __restrict__ SC,
            _Float16* __restrict__ W16)
{
  const int i = blockIdx.x * 256 + threadIdx.x;   // quad index, exact grid
  const int4 w = ((const int4*)WQ)[i];            // 16B coalesced
  const float s = SC[i >> 10];                    // 1024 quads per K-row
  f16x4 o = { (_Float16)(w.x * s), (_Float16)(w.y * s),
              (_Float16)(w.z * s), (_Float16)(w.w * s) };
  ((f16x4*)W16)[i] = o;                           // 8B coalesced
}

// ---------------- pass 1b: downcast x to fp16 ----------------
__global__ __launch_bounds__(256)
void prep_x(const float* __restrict__ X, _Float16* __restrict__ X16)
{
  const int i = blockIdx.x * 256 + threadIdx.x;
  const float4 v = ((const float4*)X)[i];
  f16x4 o = { (_Float16)v.x, (_Float16)v.y, (_Float16)v.z, (_Float16)v.w };
  ((f16x4*)X16)[i] = o;
}

// ---------------- pass 2: f16 GEMM (m97 structure) ----------------
// async global->LDS, 16B per lane. LDS dest = wave-uniform base + lane*16.
__device__ __forceinline__ void async_cp16(void* lds, const void* g) {
  auto l = (__attribute__((address_space(3))) uint32_t*)(uintptr_t)lds; // low 32b = LDS offset
  auto p = (const __attribute__((address_space(1))) uint32_t*)(uintptr_t)g;
  __builtin_amdgcn_global_load_lds(p, l, 16, 0, 0);
}

__global__ __launch_bounds__(256, 5)
void qlinear_gemm(const _Float16* __restrict__ A, const _Float16* __restrict__ B,
                  const float* __restrict__ BI, float* __restrict__ O)
{
  __shared__ __align__(16) _Float16 sA[2][BM * BK];   // 16 KB
  __shared__ __align__(16) _Float16 sB[2][BN * BK];   // 16 KB

  const int t    = threadIdx.x;
  const int lane = t & 63;
  const int wv   = t >> 6;
  const int wr   = wv >> 1;      // wave row (0..1): 64 M-rows each
  const int wc   = wv & 1;       // wave col (0..1): 64 N-cols each
  const int fr   = lane & 15;    // A/B fragment row; C col
  const int fq   = lane >> 4;    // k-group (0..3)

  // Grid swizzle: XCD-chunked (1376 = 8 * 172, exact) then bm-fastest so the
  // 16 blocks sharing one W panel run adjacently -> panel fetched once, L3-hit 15x.
  const int wg = (blockIdx.x & 7) * 172 + (blockIdx.x >> 3);
  const int m0 = (wg & 15) * BM;   // bm = wg % 16 (fastest)
  const int n0 = (wg >> 4) * BN;   // bn = wg / 16 (0..85)

  // staging: 16B chunks, chunk c = t: row (c>>2), quarter (c&3). LDS is linear
  // in chunk order (global_load_lds writes base + lane*16) == row-major [row][BK].
  const _Float16* gA0 = A + (size_t)(m0 + (t >> 2)) * K_DIM + (t & 3) * 8;
  const _Float16* gB0 = B + (size_t)(n0 + (t >> 2)) * K_DIM + (t & 3) * 8;
  const int wbase = t & 0xC0;                // wave-uniform chunk base
  _Float16* lA = &sA[0][0] + wbase * 8;      // chunk*16B = chunk*8 f16
  _Float16* lB = &sB[0][0] + wbase * 8;

  f32x4 acc[4][4] = {};

#define STAGE(buf, kt) do {                                                    \
    const int ko_ = (kt) * BK;                                                 \
    async_cp16((void*)(lA + (buf) * (BM * BK)),        gA0 + ko_);             \
    async_cp16((void*)(lA + (buf) * (BM * BK) + 2048), gA0 + (size_t)64 * K_DIM + ko_); \
    async_cp16((void*)(lB + (buf) * (BN * BK)),        gB0 + ko_);             \
    async_cp16((void*)(lB + (buf) * (BN * BK) + 2048), gB0 + (size_t)64 * K_DIM + ko_); \
  } while (0)

  STAGE(0, 0);
  __syncthreads();   // implicit vmcnt(0) drain: tile 0 ready

  for (int kt = 0; kt < NKT; ++kt) {
    const int cur = kt & 1;
    if (kt + 1 < NKT) STAGE(cur ^ 1, kt + 1);   // async prefetch overlaps compute

    const _Float16* aB = &sA[cur][0] + (wr * 64 + fr) * BK + fq * 8;
    const _Float16* bB = &sB[cur][0] + (wc * 64 + fr) * BK + fq * 8;

    f16x8 af[4], bf[4];
#pragma unroll
    for (int i = 0; i < 4; ++i) af[i] = *(const f16x8*)(aB + i * 16 * BK); // ds_read_b128
#pragma unroll
    for (int i = 0; i < 4; ++i) bf[i] = *(const f16x8*)(bB + i * 16 * BK);

#pragma unroll
    for (int mi = 0; mi < 4; ++mi)
#pragma unroll
      for (int ni = 0; ni < 4; ++ni)
        acc[mi][ni] = __builtin_amdgcn_mfma_f32_16x16x32_f16(af[mi], bf[ni], acc[mi][ni], 0, 0, 0);

    __syncthreads();  // drains prefetch vmcnt + lgkm; one barrier per K-step
  }

  // epilogue: C/D layout col=lane&15, row=(lane>>4)*4+j. Scale folded into W16.
  // Match reference rounding order: fp16(dot), then + bias in fp16, store f32.
  const int om = m0 + wr * 64;
  const int on = n0 + wc * 64;
#pragma unroll
  for (int ni = 0; ni < 4; ++ni) {
    const int n = on + ni * 16 + fr;
    const float b = BI[n];
#pragma unroll
    for (int mi = 0; mi < 4; ++mi) {
      const int m = om + mi * 16 + fq * 4;
#pragma unroll
      for (int j = 0; j < 4; ++j) {
        const _Float16 h = (_Float16)acc[mi][ni][j];        // fp16(dot)
        const _Float16 r = (_Float16)((float)h + b);        // fp16(h + bias)
        O[(size_t)(m + j) * N_DIM + n] = (float)r;
      }
    }
  }
#undef STAGE
}

extern "C" void kernel_launch(void* const* d_in, const int* in_sizes, int n_in,
                              void* d_out, int out_size, void* d_ws, size_t ws_size,
                              hipStream_t stream) {
  const float* x  = (const float*)d_in[0];
  const int*   wq = (const int*)d_in[1];
  const float* sc = (const float*)d_in[2];
  const float* bi = (const float*)d_in[3];
  float* out = (float*)d_out;

  _Float16* x16 = (_Float16*)d_ws;                                      // 16,777,216 B
  _Float16* w16 = (_Float16*)((char*)d_ws + (size_t)M_DIM * K_DIM * 2); // 90,177,536 B
  const size_t need = (size_t)M_DIM * K_DIM * 2 + (size_t)N_DIM * K_DIM * 2;
  if (ws_size < need) return;  // ws too small: leave output poisoned (clear signal)

  prep_w<<<dim3(NWQ / 256), dim3(256), 0, stream>>>(wq, sc, w16);   // 44032 blocks
  prep_x<<<dim3(NXQ / 256), dim3(256), 0, stream>>>(x, x16);        //  8192 blocks

  dim3 grid((M_DIM / BM) * (N_DIM / BN));   // 16 * 86 = 1376 blocks
  qlinear_gemm<<<grid, dim3(256), 0, stream>>>(x16, w16, bi, out);
}